// Round 1
// 252.454 us; speedup vs baseline: 1.0096x; 1.0096x over previous
//
#include <hip/hip_runtime.h>
#include <hip/hip_bf16.h>
#include <stdint.h>

// TFAttention: B=8,S=4096,N=512,K_DIM=512,HEADS=8,WS=128,HD=64
// R6: GEMMs rebuilt as 256x256-tile 8-wave deep-pipelined schedule
//     (T3 phase-split + T4 counted vmcnt + T5 setprio, per m201 template):
//     - BK=64, double-buffered 128 KiB LDS, prefetch distance 2 K-tiles
//     - per K-tile: 4 phases {ds_read quad frags; s_barrier; prio1; 16 MFMA; prio0; s_barrier}
//     - stage tile kt+2 AFTER last read of its buffer; s_waitcnt vmcnt(8) (never 0 in steady state)
//     - (row&7) chunk-XOR LDS swizzle, staged via pre-swizzled global src (linear gld_lds dst)
// Attention + cast unchanged from R4/R5.
// 16x16x32 layouts: A/B: m=lane&15, k=(lane>>4)*8+j ; C/D: col=lane&15, row=(lane>>4)*4+reg

typedef __bf16 bf16;
typedef __bf16 bf16x8 __attribute__((ext_vector_type(8)));
typedef __bf16 bf16x4 __attribute__((ext_vector_type(4)));
typedef __bf16 bf16x2 __attribute__((ext_vector_type(2)));
typedef float  f32x4  __attribute__((ext_vector_type(4)));

#define DEV static __device__ __forceinline__

DEV void gld_lds16(const bf16* g, bf16* l) {
  __builtin_amdgcn_global_load_lds(
      (__attribute__((address_space(1))) void*)(g),
      (__attribute__((address_space(3))) void*)(l), 16, 0, 0);
}

// ---------------- merged cast kernel ----------------
__global__ void cast_all(const float* __restrict__ x,
                         const float* __restrict__ Wq, const float* __restrict__ Wk,
                         const float* __restrict__ Wv, const float* __restrict__ Wp,
                         bf16* __restrict__ xb, bf16* __restrict__ wb) {
  int i = blockIdx.x * blockDim.x + threadIdx.x;
  const float* src;
  bf16* dst;
  if (i < 4194304) {
    src = x + i * 4;
    dst = xb + i * 4;
  } else {
    int e = (i - 4194304) * 4;
    int off;
    const float* w;
    if (e < 786432) {
      int seg = e >> 18;
      off = e & 262143;
      w = (seg == 0) ? Wq : ((seg == 1) ? Wk : Wv);
    } else {
      off = e - 786432;
      w = Wp;
    }
    src = w + off;
    dst = wb + e;
  }
  float4 v = *(const float4*)src;
  bf16x4 o;
  o[0] = (bf16)v.x; o[1] = (bf16)v.y; o[2] = (bf16)v.z; o[3] = (bf16)v.w;
  *(bf16x4*)dst = o;
}

// ---------------- GEMM 256x256 8-phase: C[M,NTILES*256] = A[M,512] @ B[,512]^T + bias ----------
// 512 threads = 8 waves (2 M x 4 N), each wave owns 128x64 of C.
// K = 512 -> 8 K-tiles of BK=64. LDS: 2 bufs x (A 256x64 + B 256x64) bf16 = 128 KiB.
// Phase order per tile: (qm,qn) = (0,0) -> (0,1) -> (1,1) -> (1,0)  [A/B frag reuse].
template <bool BF16OUT, int NTILES>
__global__ __launch_bounds__(512, 2)
void gemm256(const bf16* __restrict__ A, const bf16* __restrict__ B,
             const float* __restrict__ bias0, const float* __restrict__ bias1,
             const float* __restrict__ bias2, void* __restrict__ Cout) {
  constexpr int Ntot = NTILES * 256;
  __shared__ __align__(16) bf16 smem[2][2][256 * 64];  // [buf][A=0/B=1][row*64 + swz]

  const int tid = threadIdx.x;
  const int wave = tid >> 6, lane = tid & 63;
  const int wm = wave >> 2, wn = wave & 3;       // 2 x 4 wave grid
  const int lane15 = lane & 15, kq = lane >> 4;  // frag row / k-quad
  const int srow = lane >> 3, sg = (lane & 7) ^ srow;  // staging pre-swizzle

  const int nb = gridDim.x;
  const int j = blockIdx.x;
  const int l = (j & 7) * (nb >> 3) + (j >> 3);  // XCD-chunk swizzle (nb % 8 == 0)
  const long row0 = (long)(l / NTILES) * 256;
  const long col0 = (long)(l % NTILES) * 256;

  f32x4 acc[8][4] = {};
  bf16x8 af[4][2], bfr[2][2];

  // stage one K-tile t into buffer b: 8 gld_lds per thread (4 A rows-of-8, 4 B)
#define STAGE(T, BUF)                                                          \
  {                                                                            \
    const long kb_ = (long)(T) * 64;                                           \
    _Pragma("unroll") for (int i_ = 0; i_ < 4; ++i_) {                         \
      const int r0_ = wave * 32 + i_ * 8;                                      \
      gld_lds16(A + (row0 + r0_ + srow) * 512 + kb_ + sg * 8,                  \
                &smem[BUF][0][r0_ * 64]);                                      \
      gld_lds16(B + (col0 + r0_ + srow) * 512 + kb_ + sg * 8,                  \
                &smem[BUF][1][r0_ * 64]);                                      \
    }                                                                          \
  }

#define READ_A(QM, BUF)                                                        \
  {                                                                            \
    _Pragma("unroll") for (int mt_ = 0; mt_ < 4; ++mt_) {                      \
      const int r_ = wm * 128 + (QM) * 64 + mt_ * 16 + lane15;                 \
      const bf16* p_ = &smem[BUF][0][r_ * 64];                                 \
      _Pragma("unroll") for (int ks_ = 0; ks_ < 2; ++ks_) {                    \
        const int c_ = (ks_ * 4 + kq) ^ (r_ & 7);                              \
        af[mt_][ks_] = *(const bf16x8*)(p_ + c_ * 8);                          \
      }                                                                        \
    }                                                                          \
  }

#define READ_B(QN, BUF)                                                        \
  {                                                                            \
    _Pragma("unroll") for (int nt_ = 0; nt_ < 2; ++nt_) {                      \
      const int r_ = wn * 64 + (QN) * 32 + nt_ * 16 + lane15;                  \
      const bf16* p_ = &smem[BUF][1][r_ * 64];                                 \
      _Pragma("unroll") for (int ks_ = 0; ks_ < 2; ++ks_) {                    \
        const int c_ = (ks_ * 4 + kq) ^ (r_ & 7);                              \
        bfr[nt_][ks_] = *(const bf16x8*)(p_ + c_ * 8);                         \
      }                                                                        \
    }                                                                          \
  }

#define MMA_Q(QM, QN)                                                          \
  {                                                                            \
    __builtin_amdgcn_s_setprio(1);                                             \
    _Pragma("unroll") for (int mt_ = 0; mt_ < 4; ++mt_)                        \
    _Pragma("unroll") for (int nt_ = 0; nt_ < 2; ++nt_)                        \
    _Pragma("unroll") for (int ks_ = 0; ks_ < 2; ++ks_)                        \
      acc[(QM) * 4 + mt_][(QN) * 2 + nt_] =                                    \
          __builtin_amdgcn_mfma_f32_16x16x32_bf16(                             \
              af[mt_][ks_], bfr[nt_][ks_],                                     \
              acc[(QM) * 4 + mt_][(QN) * 2 + nt_], 0, 0, 0);                   \
    __builtin_amdgcn_s_setprio(0);                                             \
  }

  // prologue: tiles 0 and 1 fully staged; wait tile 0 (counted: 16 -> 8)
  STAGE(0, 0);
  STAGE(1, 1);
  asm volatile("s_waitcnt vmcnt(8)" ::: "memory");
  __builtin_amdgcn_s_barrier();

  for (int kt = 0; kt < 8; ++kt) {
    const int cur = kt & 1;
    // phase (0,0)
    READ_A(0, cur); READ_B(0, cur);
    __builtin_amdgcn_s_barrier();
    MMA_Q(0, 0);
    __builtin_amdgcn_s_barrier();
    // phase (0,1) — reuse af(qm=0)
    READ_B(1, cur);
    __builtin_amdgcn_s_barrier();
    MMA_Q(0, 1);
    __builtin_amdgcn_s_barrier();
    // phase (1,1) — reuse bfr(qn=1)
    READ_A(1, cur);
    __builtin_amdgcn_s_barrier();
    MMA_Q(1, 1);
    __builtin_amdgcn_s_barrier();
    // phase (1,0) — reuse af(qm=1)
    READ_B(0, cur);
    __builtin_amdgcn_s_barrier();
    MMA_Q(1, 0);
    __builtin_amdgcn_s_barrier();  // all reads of buf[cur] complete across waves

    // tile end: stage kt+2 into the buffer just freed; guard tile kt+1
    if (kt + 2 < 8) {
      STAGE(kt + 2, cur);
      asm volatile("s_waitcnt vmcnt(8)" ::: "memory");  // tile kt+1 landed
      __builtin_amdgcn_s_barrier();
    } else if (kt + 1 < 8) {
      asm volatile("s_waitcnt vmcnt(0)" ::: "memory");  // epilogue drain (once)
      __builtin_amdgcn_s_barrier();
    }
  }

#undef STAGE
#undef READ_A
#undef READ_B
#undef MMA_Q

  // epilogue: 16x16x32 C/D layout (col=lane&15, row=(lane>>4)*4+reg)
  const long crow = row0 + wm * 128;
  const long ccol = col0 + wn * 64;
  for (int m = 0; m < 8; ++m) {
    for (int n = 0; n < 4; ++n) {
      const long col = ccol + n * 16 + lane15;
      const float* bsel;
      if (NTILES == 6) {
        const int seg = (int)(col >> 9);
        bsel = (seg == 0) ? bias0 : ((seg == 1) ? bias1 : bias2);
      } else {
        bsel = bias0;
      }
      const float bias = bsel[col & 511];
      const long row = crow + m * 16 + kq * 4;
      for (int g = 0; g < 4; ++g) {
        const float v = acc[m][n][g] + bias;
        if (BF16OUT) ((bf16*)Cout)[(row + g) * Ntot + col] = (bf16)v;
        else         ((float*)Cout)[(row + g) * Ntot + col] = v;
      }
    }
  }
}

// ---------------- windowed attention (unchanged from R4) ----------------
__global__ __launch_bounds__(512, 4)
void attn_win(const bf16* __restrict__ QKV, bf16* __restrict__ Out) {
  __shared__ __align__(16) char smem[49152];
  bf16* Qs = (bf16*)smem;            // [128][64], chunk swizzle g^(row&7)
  bf16* Ks = Qs + 128 * 64;
  bf16* Ps = (bf16*)smem;            // [128][128], chunk swizzle g^(row&7)
  bf16* Vt = (bf16*)(smem + 32768);  // [64 d][128 t], chunk swizzle g^((d>>3)^(d&7))

  const int tid = threadIdx.x;
  const int wave = tid >> 6, lane = tid & 63;
  const int lane15 = lane & 15, quad = lane >> 4;
  const int win = blockIdx.x >> 3, head = blockIdx.x & 7;

  const bf16* Qg = QKV + (size_t)win * 128 * 1536 + head * 64;
  const bf16* Kg = Qg + 512;
  const bf16* Vg = Qg + 1024;

  {
    const int srow = lane >> 3;
    const int sg = (lane & 7) ^ srow;
    for (int i = 0; i < 2; ++i) {
      int r0 = (wave * 2 + i) * 8;
      gld_lds16(Qg + (size_t)(r0 + srow) * 1536 + sg * 8, Qs + r0 * 64 + lane * 8);
      gld_lds16(Kg + (size_t)(r0 + srow) * 1536 + sg * 8, Ks + r0 * 64 + lane * 8);
    }
  }
  {
    int tp = tid >> 3;
    int d0 = (tid & 7) * 8;
    bf16x8 v0 = *(const bf16x8*)(Vg + (size_t)(2 * tp) * 1536 + d0);
    bf16x8 v1 = *(const bf16x8*)(Vg + (size_t)(2 * tp + 1) * 1536 + d0);
    int gt = tp >> 2, po = tp & 3;
    for (int j = 0; j < 8; ++j) {
      int d = d0 + j;
      int p = gt ^ ((d >> 3) ^ (d & 7));
      bf16x2 pr;
      pr[0] = v0[j]; pr[1] = v1[j];
      *(bf16x2*)(Vt + d * 128 + p * 8 + po * 2) = pr;
    }
  }
  __syncthreads();

  f32x4 accs[8] = {};
  {
    bf16x8 aq[2];
    for (int s = 0; s < 2; ++s) {
      int row = wave * 16 + lane15;
      aq[s] = *(const bf16x8*)(Qs + row * 64 + (((s * 4 + quad) ^ (lane15 & 7)) * 8));
    }
    for (int c = 0; c < 8; ++c) {
      int row = c * 16 + lane15;
      for (int s = 0; s < 2; ++s) {
        bf16x8 bk = *(const bf16x8*)(Ks + row * 64 + (((s * 4 + quad) ^ (lane15 & 7)) * 8));
        accs[c] = __builtin_amdgcn_mfma_f32_16x16x32_bf16(aq[s], bk, accs[c], 0, 0, 0);
      }
    }
  }
  __syncthreads();

  const float scale = 0.125f;  // HD^-0.5
  for (int g = 0; g < 4; ++g) {
    float sum = 0.f;
    for (int c = 0; c < 8; ++c) {
      float e = __expf(accs[c][g] * scale);
      accs[c][g] = e;
      sum += e;
    }
    for (int mk = 1; mk <= 8; mk <<= 1) sum += __shfl_xor(sum, mk, 64);
    float inv = 1.0f / sum;
    int prow = wave * 16 + quad * 4 + g;
    int rsw = prow & 7;
    for (int c = 0; c < 8; ++c) {
      int col = c * 16 + lane15;
      int p = (col >> 3) ^ rsw;
      Ps[prow * 128 + p * 8 + (col & 7)] = (bf16)(accs[c][g] * inv);
    }
  }
  __syncthreads();

  f32x4 acco[4] = {};
  for (int kk = 0; kk < 4; ++kk) {
    int arow = wave * 16 + lane15;
    int pa = (kk * 4 + quad) ^ (arow & 7);
    bf16x8 a = *(const bf16x8*)(Ps + arow * 128 + pa * 8);
    for (int c = 0; c < 4; ++c) {
      int d = c * 16 + lane15;
      int p = (kk * 4 + quad) ^ ((d >> 3) ^ (d & 7));
      bf16x8 b = *(const bf16x8*)(Vt + d * 128 + p * 8);
      acco[c] = __builtin_amdgcn_mfma_f32_16x16x32_bf16(a, b, acco[c], 0, 0, 0);
    }
  }

  bf16* Og = Out + (size_t)win * 128 * 512 + head * 64;
  {
    int row = wave * 16 + quad * 4;
    for (int c = 0; c < 4; ++c) {
      int col = c * 16 + lane15;
      for (int g = 0; g < 4; ++g)
        Og[(size_t)(row + g) * 512 + col] = (bf16)acco[c][g];
    }
  }
}

// ---------------- launch ----------------
extern "C" void kernel_launch(void* const* d_in, const int* in_sizes, int n_in,
                              void* d_out, int out_size, void* d_ws, size_t ws_size,
                              hipStream_t stream) {
  const float* x  = (const float*)d_in[0];
  const float* Wq = (const float*)d_in[1];
  const float* bq = (const float*)d_in[2];
  const float* Wk = (const float*)d_in[3];
  const float* bk = (const float*)d_in[4];
  const float* Wv = (const float*)d_in[5];
  const float* bv = (const float*)d_in[6];
  const float* Wp = (const float*)d_in[7];
  const float* bp = (const float*)d_in[8];

  bf16* Xb    = (bf16*)d_ws;
  bf16* Wqkvb = Xb + 16777216;
  bf16* Wpb   = Wqkvb + 786432;
  bf16* QKVb  = Wpb + 262144;
  bf16* AttnB = QKVb + 50331648;

  cast_all<<<17408, 256, 0, stream>>>(x, Wq, Wk, Wv, Wp, Xb, Wqkvb);
  gemm256<true, 6><<<768, 512, 0, stream>>>(Xb, Wqkvb, bq, bk, bv, QKVb);
  attn_win<<<2048, 512, 0, stream>>>(QKVb, AttnB);
  gemm256<false, 2><<<256, 512, 0, stream>>>(AttnB, Wpb, bp, bp, bp, d_out);
}